// Round 1
// baseline (824.778 us; speedup 1.0000x reference)
//
#include <hip/hip_runtime.h>

#define HH 1024
#define WW 1024
#define HWSZ (HH * WW)
#define NITER 10

__device__ __forceinline__ float ldz(const float* __restrict__ p, int h, int w) {
    if ((unsigned)h < (unsigned)HH && (unsigned)w < (unsigned)WW) return p[h * WW + w];
    return 0.0f;
}

// cross-correlation (lax.conv does NOT flip kernels) of plane `up` with both
// 3x3 kernels in gw (gw[0..8] = kernel0, gw[9..17] = kernel1), zero pad 1.
__device__ __forceinline__ void sobel2(const float* __restrict__ up, int h, int w,
                                       const float* __restrict__ gw,
                                       float& outx, float& outy) {
    float a00 = ldz(up, h - 1, w - 1), a01 = ldz(up, h - 1, w), a02 = ldz(up, h - 1, w + 1);
    float a10 = ldz(up, h,     w - 1), a11 = up[h * WW + w],    a12 = ldz(up, h,     w + 1);
    float a20 = ldz(up, h + 1, w - 1), a21 = ldz(up, h + 1, w), a22 = ldz(up, h + 1, w + 1);
    outx = gw[0] * a00 + gw[1] * a01 + gw[2] * a02
         + gw[3] * a10 + gw[4] * a11 + gw[5] * a12
         + gw[6] * a20 + gw[7] * a21 + gw[8] * a22;
    outy = gw[9]  * a00 + gw[10] * a01 + gw[11] * a02
         + gw[12] * a10 + gw[13] * a11 + gw[14] * a12
         + gw[15] * a20 + gw[16] * a21 + gw[17] * a22;
}

// Precompute rho_c, grad_im (g0,g1); zero u (in d_out), p (4 planes), S slots.
__global__ __launch_bounds__(256) void k_pre(const float* __restrict__ x,
                                             const float* __restrict__ gw,
                                             float* __restrict__ rho_c,
                                             float* __restrict__ g0,
                                             float* __restrict__ g1,
                                             float* __restrict__ p,
                                             float* __restrict__ u,
                                             float* __restrict__ S) {
    int idx = blockIdx.x * blockDim.x + threadIdx.x;
    if (idx >= HWSZ) return;
    int h = idx >> 10, w = idx & (WW - 1);
    const float* x0 = x;
    const float* x1 = x + HWSZ;
    float gx, gy;
    sobel2(x1, h, w, gw, gx, gy);
    g0[idx] = gx;
    g1[idx] = gy;
    rho_c[idx] = x1[idx] - x0[idx];
    u[idx] = 0.0f;
    u[idx + HWSZ] = 0.0f;
    p[idx] = 0.0f;
    p[idx + HWSZ] = 0.0f;
    p[idx + 2 * HWSZ] = 0.0f;
    p[idx + 3 * HWSZ] = 0.0f;
    if (idx < 16) S[idx] = 0.0f;
}

// u update: rho/thresholding (v) + theta*(div_x + div_y). In-place on u.
__global__ __launch_bounds__(256) void k_u(const float* __restrict__ rho_c,
                                           const float* __restrict__ g0p,
                                           const float* __restrict__ g1p,
                                           const float* __restrict__ p,
                                           float* __restrict__ u,
                                           const float* __restrict__ lam,
                                           const float* __restrict__ tau_,
                                           const float* __restrict__ theta_,
                                           const float* __restrict__ wx,
                                           const float* __restrict__ wy) {
    int idx = blockIdx.x * blockDim.x + threadIdx.x;
    if (idx >= HWSZ) return;
    int h = idx >> 10, w = idx & (WW - 1);
    float theta = theta_[0];
    float tl = theta * lam[0];

    float g0 = g0p[idx], g1 = g1p[idx];
    float ng = g0 * g0 + g1 * g1;
    float u0 = u[idx], u1 = u[idx + HWSZ];
    float rho = rho_c[idx] + g0 * u0 + g1 * u1;
    float a = fabsf(rho);
    float th = tl * ng;
    float sgn = (rho > 0.0f) ? 1.0f : ((rho < 0.0f) ? -1.0f : 0.0f);
    float d0 = 0.0f, d1 = 0.0f;
    if (a < th) {
        d0 = rho * g0 / ng;
        d1 = rho * g1 / ng;
    } else if (a > th) {
        d0 = tl * g0 * sgn;
        d1 = tl * g1 * sgn;
    }
    float v0 = u0 - d0, v1 = u1 - d1;

    const float* p00 = p;               // p[0][0] -> div_x for channel 0
    const float* p01 = p + HWSZ;        // p[0][1] -> div_x for channel 1
    const float* p10 = p + 2 * HWSZ;    // p[1][0] -> div_y for channel 0
    const float* p11 = p + 3 * HWSZ;    // p[1][1] -> div_y for channel 1
    float wx0 = wx[0], wx1 = wx[1];
    float wy0 = wy[0], wy1 = wy[1];
    float divx0 = wx1 * p00[idx] + ((w > 0) ? wx0 * p00[idx - 1] : 0.0f);
    float divx1 = wx1 * p01[idx] + ((w > 0) ? wx0 * p01[idx - 1] : 0.0f);
    float divy0 = wy1 * p10[idx] + ((h > 0) ? wy0 * p10[idx - WW] : 0.0f);
    float divy1 = wy1 * p11[idx] + ((h > 0) ? wy0 * p11[idx - WW] : 0.0f);

    u[idx]        = v0 + theta * (divx0 + divy0);
    u[idx + HWSZ] = v1 + theta * (divx1 + divy1);
}

// global sum of |gradu| over both channels, both derivative kernels -> S[0]
__global__ __launch_bounds__(256) void k_sum(const float* __restrict__ u,
                                             const float* __restrict__ gw,
                                             float* __restrict__ Sp) {
    int idx = blockIdx.x * blockDim.x + threadIdx.x;
    float local = 0.0f;
    if (idx < HWSZ) {
        int h = idx >> 10, w = idx & (WW - 1);
        float gx0, gy0, gx1, gy1;
        sobel2(u, h, w, gw, gx0, gy0);
        sobel2(u + HWSZ, h, w, gw, gx1, gy1);
        local = fabsf(gx0) + fabsf(gy0) + fabsf(gx1) + fabsf(gy1);
    }
    // wave (64) + block (256) reduction
    float v = local;
    #pragma unroll
    for (int off = 32; off > 0; off >>= 1) v += __shfl_down(v, off, 64);
    __shared__ float sm[4];
    int lane = threadIdx.x & 63, wid = threadIdx.x >> 6;
    if (lane == 0) sm[wid] = v;
    __syncthreads();
    if (threadIdx.x == 0) {
        float s = sm[0] + sm[1] + sm[2] + sm[3];
        atomicAdd(Sp, s);
    }
}

// p update: p = (p + r*gradu) / (1 + r*S); gradu recomputed from u stencil.
__global__ __launch_bounds__(256) void k_p(const float* __restrict__ u,
                                           const float* __restrict__ gw,
                                           float* __restrict__ p,
                                           const float* __restrict__ Sp,
                                           const float* __restrict__ tau_,
                                           const float* __restrict__ theta_) {
    int idx = blockIdx.x * blockDim.x + threadIdx.x;
    if (idx >= HWSZ) return;
    int h = idx >> 10, w = idx & (WW - 1);
    float r = tau_[0] / theta_[0];
    float denom = 1.0f + r * Sp[0];
    float gx0, gy0, gx1, gy1;
    sobel2(u, h, w, gw, gx0, gy0);           // gradu[0][0], gradu[0][1]
    sobel2(u + HWSZ, h, w, gw, gx1, gy1);    // gradu[1][0], gradu[1][1]
    p[idx]            = (p[idx]            + r * gx0) / denom;
    p[idx + HWSZ]     = (p[idx + HWSZ]     + r * gy0) / denom;
    p[idx + 2 * HWSZ] = (p[idx + 2 * HWSZ] + r * gx1) / denom;
    p[idx + 3 * HWSZ] = (p[idx + 3 * HWSZ] + r * gy1) / denom;
}

extern "C" void kernel_launch(void* const* d_in, const int* in_sizes, int n_in,
                              void* d_out, int out_size, void* d_ws, size_t ws_size,
                              hipStream_t stream) {
    const float* x     = (const float*)d_in[0];
    const float* gw    = (const float*)d_in[1];
    const float* wx    = (const float*)d_in[2];
    const float* wy    = (const float*)d_in[3];
    const float* lam   = (const float*)d_in[4];
    const float* tau   = (const float*)d_in[5];
    const float* theta = (const float*)d_in[6];

    float* u  = (float*)d_out;          // u lives in d_out (2 planes)
    float* ws = (float*)d_ws;
    float* rho_c = ws;                  // 1 plane
    float* g0    = ws + HWSZ;           // 1 plane
    float* g1    = ws + 2 * (size_t)HWSZ;  // 1 plane
    float* p     = ws + 3 * (size_t)HWSZ;  // 4 planes
    float* S     = ws + 7 * (size_t)HWSZ;  // 16 floats (one slot per iter)

    dim3 block(256);
    dim3 grid(HWSZ / 256);
    k_pre<<<grid, block, 0, stream>>>(x, gw, rho_c, g0, g1, p, u, S);
    for (int t = 0; t < NITER; ++t) {
        k_u<<<grid, block, 0, stream>>>(rho_c, g0, g1, p, u, lam, tau, theta, wx, wy);
        k_sum<<<grid, block, 0, stream>>>(u, gw, S + t);
        k_p<<<grid, block, 0, stream>>>(u, gw, p, S + t, tau, theta);
    }
}

// Round 2
// 354.119 us; speedup vs baseline: 2.3291x; 2.3291x over previous
//
#include <hip/hip_runtime.h>

#define HH 1024
#define WW 1024
#define HWSZ (HH * WW)
#define NV (HWSZ / 4)       // vec4 groups per plane
#define NITER 10

// load 6 columns (w-1 .. w+4) of row h from plane, zero-padded
__device__ __forceinline__ void row6(const float* __restrict__ pl, int h, int w, float a[6]) {
    if ((unsigned)h < (unsigned)HH) {
        const float* rp = pl + h * WW + w;
        const float4 v = *(const float4*)rp;
        a[0] = (w > 0) ? rp[-1] : 0.0f;
        a[1] = v.x; a[2] = v.y; a[3] = v.z; a[4] = v.w;
        a[5] = (w + 4 < WW) ? rp[4] : 0.0f;
    } else {
        a[0] = a[1] = a[2] = a[3] = a[4] = a[5] = 0.0f;
    }
}

// 3x3 cross-correlation (both kernels) for 4 consecutive pixels
__device__ __forceinline__ void sobel4(const float* __restrict__ plane, int h, int w,
                                       const float kx[9], const float ky[9],
                                       float gx[4], float gy[4]) {
    float t[6], m[6], b[6];
    row6(plane, h - 1, w, t);
    row6(plane, h,     w, m);
    row6(plane, h + 1, w, b);
    #pragma unroll
    for (int i = 0; i < 4; ++i) {
        gx[i] = kx[0] * t[i] + kx[1] * t[i + 1] + kx[2] * t[i + 2]
              + kx[3] * m[i] + kx[4] * m[i + 1] + kx[5] * m[i + 2]
              + kx[6] * b[i] + kx[7] * b[i + 1] + kx[8] * b[i + 2];
        gy[i] = ky[0] * t[i] + ky[1] * t[i + 1] + ky[2] * t[i + 2]
              + ky[3] * m[i] + ky[4] * m[i + 1] + ky[5] * m[i + 2]
              + ky[6] * b[i] + ky[7] * b[i + 1] + ky[8] * b[i + 2];
    }
}

__device__ __forceinline__ void load_k(const float* __restrict__ gw, float kx[9], float ky[9]) {
    #pragma unroll
    for (int i = 0; i < 9; ++i) { kx[i] = gw[i]; ky[i] = gw[9 + i]; }
}

// Precompute rho_c, grad_im; zero u, p, S.
__global__ __launch_bounds__(256) void k_pre(const float* __restrict__ x,
                                             const float* __restrict__ gw,
                                             float* __restrict__ rho_c,
                                             float* __restrict__ g0,
                                             float* __restrict__ g1,
                                             float* __restrict__ p,
                                             float* __restrict__ u,
                                             float* __restrict__ S) {
    int v = blockIdx.x * blockDim.x + threadIdx.x;
    if (v >= NV) return;
    int idx = v * 4;
    int h = idx >> 10, w = idx & (WW - 1);
    float kx[9], ky[9];
    load_k(gw, kx, ky);
    const float* x0 = x;
    const float* x1 = x + HWSZ;
    float gx[4], gy[4];
    sobel4(x1, h, w, kx, ky, gx, gy);
    *(float4*)(g0 + idx) = make_float4(gx[0], gx[1], gx[2], gx[3]);
    *(float4*)(g1 + idx) = make_float4(gy[0], gy[1], gy[2], gy[3]);
    float4 a = *(const float4*)(x1 + idx);
    float4 c = *(const float4*)(x0 + idx);
    *(float4*)(rho_c + idx) = make_float4(a.x - c.x, a.y - c.y, a.z - c.z, a.w - c.w);
    float4 z = make_float4(0.f, 0.f, 0.f, 0.f);
    *(float4*)(u + idx) = z;
    *(float4*)(u + HWSZ + idx) = z;
    *(float4*)(p + idx) = z;
    *(float4*)(p + HWSZ + idx) = z;
    *(float4*)(p + 2 * HWSZ + idx) = z;
    *(float4*)(p + 3 * HWSZ + idx) = z;
    if (v < 16) S[v] = 0.0f;
}

// per-pixel threshold step -> v0,v1
__device__ __forceinline__ float2 vupd(float rc, float g0, float g1,
                                       float u0, float u1, float tl) {
    float ng = g0 * g0 + g1 * g1;
    float rho = rc + g0 * u0 + g1 * u1;
    float a = fabsf(rho);
    float th = tl * ng;
    float sgn = (rho > 0.0f) ? 1.0f : ((rho < 0.0f) ? -1.0f : 0.0f);
    float d0 = 0.0f, d1 = 0.0f;
    if (a < th) { float s = rho / ng; d0 = s * g0; d1 = s * g1; }
    else if (a > th) { d0 = tl * g0 * sgn; d1 = tl * g1 * sgn; }
    return make_float2(u0 - d0, u1 - d1);
}

// u update (in-place): v + theta*(div_x + div_y)
__global__ __launch_bounds__(256) void k_u(const float* __restrict__ rho_c,
                                           const float* __restrict__ g0p,
                                           const float* __restrict__ g1p,
                                           const float* __restrict__ p,
                                           float* __restrict__ u,
                                           const float* __restrict__ lam,
                                           const float* __restrict__ theta_,
                                           const float* __restrict__ wx,
                                           const float* __restrict__ wy) {
    int v = blockIdx.x * blockDim.x + threadIdx.x;
    if (v >= NV) return;
    int idx = v * 4;
    int h = idx >> 10, w = idx & (WW - 1);
    float theta = theta_[0];
    float tl = theta * lam[0];
    float wx0 = wx[0], wx1 = wx[1];
    float wy0 = wy[0], wy1 = wy[1];

    float4 g0v = *(const float4*)(g0p + idx);
    float4 g1v = *(const float4*)(g1p + idx);
    float4 rcv = *(const float4*)(rho_c + idx);
    float4 u0v = *(const float4*)(u + idx);
    float4 u1v = *(const float4*)(u + HWSZ + idx);

    float2 r0 = vupd(rcv.x, g0v.x, g1v.x, u0v.x, u1v.x, tl);
    float2 r1 = vupd(rcv.y, g0v.y, g1v.y, u0v.y, u1v.y, tl);
    float2 r2 = vupd(rcv.z, g0v.z, g1v.z, u0v.z, u1v.z, tl);
    float2 r3 = vupd(rcv.w, g0v.w, g1v.w, u0v.w, u1v.w, tl);

    const float* p00 = p;
    const float* p01 = p + HWSZ;
    const float* p10 = p + 2 * HWSZ;
    const float* p11 = p + 3 * HWSZ;
    float4 a00 = *(const float4*)(p00 + idx);
    float4 a01 = *(const float4*)(p01 + idx);
    float4 a10 = *(const float4*)(p10 + idx);
    float4 a11 = *(const float4*)(p11 + idx);
    float a00l = (w > 0) ? p00[idx - 1] : 0.0f;
    float a01l = (w > 0) ? p01[idx - 1] : 0.0f;
    float4 zz = make_float4(0.f, 0.f, 0.f, 0.f);
    float4 a10u = (h > 0) ? *(const float4*)(p10 + idx - WW) : zz;
    float4 a11u = (h > 0) ? *(const float4*)(p11 + idx - WW) : zz;

    // div_x: wx1*p[w] + wx0*p[w-1];  div_y: wy1*p[h] + wy0*p[h-1]
    float dx0_0 = wx1 * a00.x + wx0 * a00l;
    float dx0_1 = wx1 * a00.y + wx0 * a00.x;
    float dx0_2 = wx1 * a00.z + wx0 * a00.y;
    float dx0_3 = wx1 * a00.w + wx0 * a00.z;
    float dx1_0 = wx1 * a01.x + wx0 * a01l;
    float dx1_1 = wx1 * a01.y + wx0 * a01.x;
    float dx1_2 = wx1 * a01.z + wx0 * a01.y;
    float dx1_3 = wx1 * a01.w + wx0 * a01.z;
    float dy0_0 = wy1 * a10.x + wy0 * a10u.x;
    float dy0_1 = wy1 * a10.y + wy0 * a10u.y;
    float dy0_2 = wy1 * a10.z + wy0 * a10u.z;
    float dy0_3 = wy1 * a10.w + wy0 * a10u.w;
    float dy1_0 = wy1 * a11.x + wy0 * a11u.x;
    float dy1_1 = wy1 * a11.y + wy0 * a11u.y;
    float dy1_2 = wy1 * a11.z + wy0 * a11u.z;
    float dy1_3 = wy1 * a11.w + wy0 * a11u.w;

    *(float4*)(u + idx) = make_float4(r0.x + theta * (dx0_0 + dy0_0),
                                      r1.x + theta * (dx0_1 + dy0_1),
                                      r2.x + theta * (dx0_2 + dy0_2),
                                      r3.x + theta * (dx0_3 + dy0_3));
    *(float4*)(u + HWSZ + idx) = make_float4(r0.y + theta * (dx1_0 + dy1_0),
                                             r1.y + theta * (dx1_1 + dy1_1),
                                             r2.y + theta * (dx1_2 + dy1_2),
                                             r3.y + theta * (dx1_3 + dy1_3));
}

// global sum |gradu| -> S (256 blocks, 4 vec4-groups per thread, 1 atomic/block)
__global__ __launch_bounds__(256) void k_sum(const float* __restrict__ u,
                                             const float* __restrict__ gw,
                                             float* __restrict__ Sp) {
    float kx[9], ky[9];
    load_k(gw, kx, ky);
    int base = blockIdx.x * 256 + threadIdx.x;   // [0, 65536)
    float local = 0.0f;
    #pragma unroll
    for (int j = 0; j < 4; ++j) {
        int v = base + j * 65536;
        int idx = v * 4;
        int h = idx >> 10, w = idx & (WW - 1);
        float gx0[4], gy0[4], gx1[4], gy1[4];
        sobel4(u, h, w, kx, ky, gx0, gy0);
        sobel4(u + HWSZ, h, w, kx, ky, gx1, gy1);
        #pragma unroll
        for (int i = 0; i < 4; ++i)
            local += fabsf(gx0[i]) + fabsf(gy0[i]) + fabsf(gx1[i]) + fabsf(gy1[i]);
    }
    float s = local;
    #pragma unroll
    for (int off = 32; off > 0; off >>= 1) s += __shfl_down(s, off, 64);
    __shared__ float sm[4];
    int lane = threadIdx.x & 63, wid = threadIdx.x >> 6;
    if (lane == 0) sm[wid] = s;
    __syncthreads();
    if (threadIdx.x == 0) atomicAdd(Sp, sm[0] + sm[1] + sm[2] + sm[3]);
}

// p update: p = (p + r*gradu) / (1 + r*S)
__global__ __launch_bounds__(256) void k_p(const float* __restrict__ u,
                                           const float* __restrict__ gw,
                                           float* __restrict__ p,
                                           const float* __restrict__ Sp,
                                           const float* __restrict__ tau_,
                                           const float* __restrict__ theta_) {
    int v = blockIdx.x * blockDim.x + threadIdx.x;
    if (v >= NV) return;
    int idx = v * 4;
    int h = idx >> 10, w = idx & (WW - 1);
    float kx[9], ky[9];
    load_k(gw, kx, ky);
    float r = tau_[0] / theta_[0];
    float denom = 1.0f + r * Sp[0];
    float inv = 1.0f / denom;
    float gx0[4], gy0[4], gx1[4], gy1[4];
    sobel4(u, h, w, kx, ky, gx0, gy0);
    sobel4(u + HWSZ, h, w, kx, ky, gx1, gy1);

    float4 q0 = *(const float4*)(p + idx);
    float4 q1 = *(const float4*)(p + HWSZ + idx);
    float4 q2 = *(const float4*)(p + 2 * HWSZ + idx);
    float4 q3 = *(const float4*)(p + 3 * HWSZ + idx);
    q0 = make_float4((q0.x + r * gx0[0]) * inv, (q0.y + r * gx0[1]) * inv,
                     (q0.z + r * gx0[2]) * inv, (q0.w + r * gx0[3]) * inv);
    q1 = make_float4((q1.x + r * gy0[0]) * inv, (q1.y + r * gy0[1]) * inv,
                     (q1.z + r * gy0[2]) * inv, (q1.w + r * gy0[3]) * inv);
    q2 = make_float4((q2.x + r * gx1[0]) * inv, (q2.y + r * gx1[1]) * inv,
                     (q2.z + r * gx1[2]) * inv, (q2.w + r * gx1[3]) * inv);
    q3 = make_float4((q3.x + r * gy1[0]) * inv, (q3.y + r * gy1[1]) * inv,
                     (q3.z + r * gy1[2]) * inv, (q3.w + r * gy1[3]) * inv);
    *(float4*)(p + idx) = q0;
    *(float4*)(p + HWSZ + idx) = q1;
    *(float4*)(p + 2 * HWSZ + idx) = q2;
    *(float4*)(p + 3 * HWSZ + idx) = q3;
}

extern "C" void kernel_launch(void* const* d_in, const int* in_sizes, int n_in,
                              void* d_out, int out_size, void* d_ws, size_t ws_size,
                              hipStream_t stream) {
    const float* x     = (const float*)d_in[0];
    const float* gw    = (const float*)d_in[1];
    const float* wx    = (const float*)d_in[2];
    const float* wy    = (const float*)d_in[3];
    const float* lam   = (const float*)d_in[4];
    const float* tau   = (const float*)d_in[5];
    const float* theta = (const float*)d_in[6];

    float* u  = (float*)d_out;                 // 2 planes
    float* ws = (float*)d_ws;
    float* rho_c = ws;                         // 1 plane
    float* g0    = ws + (size_t)HWSZ;          // 1 plane
    float* g1    = ws + 2 * (size_t)HWSZ;      // 1 plane
    float* p     = ws + 3 * (size_t)HWSZ;      // 4 planes
    float* S     = ws + 7 * (size_t)HWSZ;      // NITER slots

    dim3 block(256);
    dim3 gridV(NV / 256);                      // 1024 blocks
    dim3 gridS(256);                           // k_sum: 256 blocks
    k_pre<<<gridV, block, 0, stream>>>(x, gw, rho_c, g0, g1, p, u, S);
    for (int t = 0; t < NITER; ++t) {
        k_u<<<gridV, block, 0, stream>>>(rho_c, g0, g1, p, u, lam, theta, wx, wy);
        k_sum<<<gridS, block, 0, stream>>>(u, gw, S + t);
        k_p<<<gridV, block, 0, stream>>>(u, gw, p, S + t, tau, theta);
    }
}